// Round 3
// baseline (78.983 us; speedup 1.0000x reference)
//
#include <hip/hip_runtime.h>

// B=256, N=25, C=256, H/2=128.
// Telescoping: edge_feat[b,i,j,:] = src[b,j]-src[b,i]  =>  u = src @ W1^T (MFMA).
// PReLU identity: max(d,0)=max(uj,ui)-ui  =>
//   out[i,j] = (1-a)*M[i,j] + a*s_j - s_i,  M[i,j]=sum_h w2*max(uj,ui) (SYMMETRIC),
//   s_i = sum_h w2*u_i.  So only 300 upper-tri M's needed; diag is exactly 0.
#define NJ    25
#define CIN   256
#define HH    128
#define AS    264          // a_s row stride in shorts (528B -> conflict-free MFMA frag reads)
#define NPAIR 300          // upper triangle i<j
#define HALFP 150

typedef __attribute__((ext_vector_type(8))) short short8;
typedef __attribute__((ext_vector_type(4))) float f32x4;

__device__ __forceinline__ unsigned short f2bf(float f) {
    union { float f; unsigned u; } v; v.f = f;
    unsigned r = v.u + 0x7FFF + ((v.u >> 16) & 1);   // RNE
    return (unsigned short)(r >> 16);
}
__device__ __forceinline__ float bf2f(short s) {
    union { unsigned u; float f; } v;
    v.u = ((unsigned)(unsigned short)s) << 16;
    return v.f;
}

__global__ __launch_bounds__(512) void fused_edge_mlp_v3(
    const float* __restrict__ src,   // [B,25,256]
    const float* __restrict__ W1,    // [128,256]
    const float* __restrict__ Aarr,  // [1] alpha
    const float* __restrict__ W2,    // [128]
    float* __restrict__ out)         // [B,25,25]
{
    __shared__ short a_s[32 * AS];          // src[b] bf16, rows 25..31 zero (16.9 KB)
    __shared__ short u8s[16 * 26 * 8];      // u bf16: [h8][joint][8h] (6.7 KB)

    const int b    = blockIdx.x >> 1;       // batch
    const int hb   = blockIdx.x & 1;        // which half of the pair triangle
    const int t    = threadIdx.x;

    // ---------------- Phase 0: stage src[b] -> LDS bf16 ----------------------------
    {
        unsigned* au = (unsigned*)a_s;
        for (int i = (25 * AS) / 2 + t; i < (32 * AS) / 2; i += 512) au[i] = 0u;
        const float4* s4 = reinterpret_cast<const float4*>(src) + (long)b * (NJ * CIN / 4);
        for (int idx = t; idx < NJ * CIN / 4; idx += 512) {
            int n  = idx >> 6;
            int k4 = idx & 63;
            float4 v = s4[idx];
            unsigned lo = (unsigned)f2bf(v.x) | ((unsigned)f2bf(v.y) << 16);
            unsigned hi = (unsigned)f2bf(v.z) | ((unsigned)f2bf(v.w) << 16);
            *(uint2*)&a_s[n * AS + k4 * 4] = make_uint2(lo, hi);
        }
    }
    __syncthreads();

    // ---------------- Phase 1: u = src_bf16 @ W1_bf16^T via MFMA -------------------
    {
        const int w    = t >> 6;         // wave id = h N-tile (16 cols)
        const int lane = t & 63;
        const int ln15 = lane & 15;
        const int quad = lane >> 4;
        const int hcol = w * 16 + ln15;

        short8 bfrag[8];
        const float* w1row = W1 + hcol * CIN;
        #pragma unroll
        for (int kt = 0; kt < 8; ++kt) {
            const float* p = w1row + kt * 32 + quad * 8;
            float4 x = *reinterpret_cast<const float4*>(p);
            float4 y = *reinterpret_cast<const float4*>(p + 4);
            short8 bf;
            bf[0] = (short)f2bf(x.x); bf[1] = (short)f2bf(x.y);
            bf[2] = (short)f2bf(x.z); bf[3] = (short)f2bf(x.w);
            bf[4] = (short)f2bf(y.x); bf[5] = (short)f2bf(y.y);
            bf[6] = (short)f2bf(y.z); bf[7] = (short)f2bf(y.w);
            bfrag[kt] = bf;
        }

        f32x4 acc0 = {0.f, 0.f, 0.f, 0.f};
        f32x4 acc1 = {0.f, 0.f, 0.f, 0.f};
        #pragma unroll
        for (int kt = 0; kt < 8; ++kt) {
            const int ko = kt * 32 + quad * 8;
            short8 a0 = *reinterpret_cast<const short8*>(&a_s[(ln15)      * AS + ko]);
            short8 a1 = *reinterpret_cast<const short8*>(&a_s[(16 + ln15) * AS + ko]);
            acc0 = __builtin_amdgcn_mfma_f32_16x16x32_bf16(a0, bfrag[kt], acc0, 0, 0, 0);
            acc1 = __builtin_amdgcn_mfma_f32_16x16x32_bf16(a1, bfrag[kt], acc1, 0, 0, 0);
        }

        // D layout: col(h)=lane&15, row(m)=quad*4+reg.
        const int h8  = hcol >> 3;
        const int hlo = hcol & 7;
        #pragma unroll
        for (int r = 0; r < 4; ++r) {
            int m0 = quad * 4 + r;
            if (m0 < NJ) u8s[(h8 * 26 + m0) * 8 + hlo] = (short)f2bf(acc0[r]);
            int m1 = 16 + quad * 4 + r;
            if (m1 < NJ) u8s[(h8 * 26 + m1) * 8 + hlo] = (short)f2bf(acc1[r]);
        }
    }
    __syncthreads();

    // ---------------- Phase 2: 150 upper-tri pairs per block -----------------------
    const float alpha = Aarr[0];
    float* outb = out + (long)b * (NJ * NJ);

    if (t < HALFP) {
        const int p = hb * HALFP + t;
        // row i of upper triangle: S(i) = (49i - i^2)/2 entries precede row i
        int i = (int)((49.0f - sqrtf(2401.0f - 8.0f * (float)p)) * 0.5f);
        {   // fp-safety clamp
            int Si = (49 * i - i * i) >> 1;
            if (p < Si) { --i; }
            else { int Sn = (49 * (i + 1) - (i + 1) * (i + 1)) >> 1; if (p >= Sn) ++i; }
        }
        const int S  = (49 * i - i * i) >> 1;
        const int j  = p - S + i + 1;

        float M = 0.f, sj = 0.f, si = 0.f;
        #pragma unroll 4
        for (int h8 = 0; h8 < 16; ++h8) {
            short8 uj8 = *reinterpret_cast<const short8*>(&u8s[(h8 * 26 + j) * 8]);
            short8 ui8 = *reinterpret_cast<const short8*>(&u8s[(h8 * 26 + i) * 8]);
            const float* w2p = W2 + h8 * 8;   // uniform -> s_load
            #pragma unroll
            for (int q = 0; q < 8; ++q) {
                float fj = bf2f(uj8[q]);
                float fi = bf2f(ui8[q]);
                float w  = w2p[q];
                M  = fmaf(w, fmaxf(fi, fj), M);
                sj = fmaf(w, fj, sj);
                si = fmaf(w, fi, si);
            }
        }
        const float Mw = (1.f - alpha) * M;
        outb[i * NJ + j] = Mw + alpha * sj - si;
        outb[j * NJ + i] = Mw + alpha * si - sj;
    } else if (hb == 0 && t < HALFP + NJ) {
        const int i = t - HALFP;
        outb[i * NJ + i] = 0.f;               // diagonal: d=0 -> prelu=0 exactly
    }
}

extern "C" void kernel_launch(void* const* d_in, const int* in_sizes, int n_in,
                              void* d_out, int out_size, void* d_ws, size_t ws_size,
                              hipStream_t stream) {
    // inputs: 0=src, 1=heads, 2=ends, 3=pair_ids (unused: telescoping), 4=W1, 5=alpha, 6=W2
    const float* src   = (const float*)d_in[0];
    const float* W1    = (const float*)d_in[4];
    const float* alpha = (const float*)d_in[5];
    const float* W2    = (const float*)d_in[6];
    float* out = (float*)d_out;

    const int B = in_sizes[0] / (NJ * CIN);   // 256
    fused_edge_mlp_v3<<<B * 2, 512, 0, stream>>>(src, W1, alpha, W2, out);
}

// Round 4
// 74.620 us; speedup vs baseline: 1.0585x; 1.0585x over previous
//
#include <hip/hip_runtime.h>

// B=256, N=25, C=256, H/2=128.
// Telescoping: edge_feat[b,i,j,:] = src[b,j]-src[b,i]  =>  u = src @ W1^T (bf16 MFMA).
// PReLU identity: max(d,0)=max(uj,ui)-ui =>
//   out[i,j] = (1-a)*M[i,j] + a*s_j - s_i,   M[i,j]=sum_h w2*max(uj,ui) (symmetric),
//   s_i = sum_h w2*u_i ; diagonal is exactly 0. Only 300 upper-tri pairs computed.
//
// R4 structure: prep kernel pre-converts src and W1 to bf16 *in MFMA fragment
// lane order* in d_ws, so the main kernel's global loads are contiguous
// 1KB-per-wave b128s (16 cache lines/instr) instead of 16-row gathers
// (~32 lines/instr) — removes the vmem-pipe serialization that R2/R3 hit.
#define NJ   25
#define CIN  256
#define HH   128

typedef __attribute__((ext_vector_type(8))) short short8;
typedef __attribute__((ext_vector_type(4))) float f32x4;

__device__ __forceinline__ unsigned short f2bf(float f) {
    union { float f; unsigned u; } v; v.f = f;
    unsigned r = v.u + 0x7FFF + ((v.u >> 16) & 1);   // RNE
    return (unsigned short)(r >> 16);
}
__device__ __forceinline__ unsigned pack2(float a, float b) {
    return (unsigned)f2bf(a) | ((unsigned)f2bf(b) << 16);
}

// ---------------- Kernel A: fragment-layout pre-conversion ----------------------
// srcfrag[((b*16 + mt*8 + kt)*64 + lane)*8] = bf16 src[b][mt*16+(lane&15)][kt*32+(lane>>4)*8 ..+7]
// w1frag [((nt*8 + kt)*64 + lane)*8]        = bf16 W1[nt*16+(lane&15)][kt*32+(lane>>4)*8 ..+7]
__global__ __launch_bounds__(256) void prep_frags(
    const float* __restrict__ src, const float* __restrict__ W1,
    unsigned short* __restrict__ srcfrag, unsigned short* __restrict__ w1frag,
    int nsrc)
{
    const int gid = blockIdx.x * 256 + threadIdx.x;
    const float* base;
    unsigned short* dst;
    if (gid < nsrc) {
        const int lane = gid & 63, kt = (gid >> 6) & 7, mt = (gid >> 9) & 1, b = gid >> 10;
        const int row = mt * 16 + (lane & 15);
        const int k0  = kt * 32 + (lane >> 4) * 8;
        dst = srcfrag + (size_t)gid * 8;
        if (row >= NJ) { *(uint4*)dst = make_uint4(0u, 0u, 0u, 0u); return; }
        base = src + ((size_t)b * NJ + row) * CIN + k0;
    } else {
        const int id = gid - nsrc;
        if (id >= 4096) return;
        const int lane = id & 63, kt = (id >> 6) & 7, nt = id >> 9;
        const int row = nt * 16 + (lane & 15);
        const int k0  = kt * 32 + (lane >> 4) * 8;
        dst = w1frag + (size_t)id * 8;
        base = W1 + (size_t)row * CIN + k0;
    }
    float4 x = *(const float4*)base;
    float4 y = *(const float4*)(base + 4);
    uint4 o;
    o.x = pack2(x.x, x.y); o.y = pack2(x.z, x.w);
    o.z = pack2(y.x, y.y); o.w = pack2(y.z, y.w);
    *(uint4*)dst = o;
}

// ---------------- Kernel B: MFMA u-GEMM + pair epilogue -------------------------
__global__ __launch_bounds__(512) void fused_edge_mlp_v4(
    const unsigned short* __restrict__ srcfrag,
    const unsigned short* __restrict__ w1frag,
    const float* __restrict__ Aarr,   // [1] alpha
    const float* __restrict__ W2,     // [128]
    float* __restrict__ out)          // [B,25,25]
{
    __shared__ float u_s[NJ * 132];   // u fp32, row stride 132 (13.2 KB)

    const int b    = blockIdx.x;
    const int t    = threadIdx.x;
    const int w    = t >> 6;          // wave = h N-tile (16 cols)
    const int lane = t & 63;
    const int ln15 = lane & 15;
    const int quad = lane >> 4;

    // Phase 1: u = src_bf16 @ W1_bf16^T.  All loads contiguous per wave (1KB/instr).
    {
        const short8* w1p = (const short8*)w1frag + (w * 8) * 64 + lane;
        const short8* ap  = (const short8*)srcfrag + ((size_t)b * 16) * 64 + lane;

        short8 bfrag[8];
        #pragma unroll
        for (int kt = 0; kt < 8; ++kt) bfrag[kt] = w1p[kt * 64];

        f32x4 acc0 = {0.f, 0.f, 0.f, 0.f};
        f32x4 acc1 = {0.f, 0.f, 0.f, 0.f};
        #pragma unroll
        for (int kt = 0; kt < 8; ++kt) {
            short8 a0 = ap[kt * 64];          // mt=0 rows 0..15
            short8 a1 = ap[(8 + kt) * 64];    // mt=1 rows 16..31 (25..31 zero)
            acc0 = __builtin_amdgcn_mfma_f32_16x16x32_bf16(a0, bfrag[kt], acc0, 0, 0, 0);
            acc1 = __builtin_amdgcn_mfma_f32_16x16x32_bf16(a1, bfrag[kt], acc1, 0, 0, 0);
        }

        // D layout: col(h)=lane&15, row(m)=quad*4+reg
        const int hcol = w * 16 + ln15;
        #pragma unroll
        for (int r = 0; r < 4; ++r) {
            int m0 = quad * 4 + r;
            if (m0 < NJ) u_s[m0 * 132 + hcol] = acc0[r];
            int m1 = 16 + quad * 4 + r;
            if (m1 < NJ) u_s[m1 * 132 + hcol] = acc1[r];
        }
    }
    __syncthreads();

    // Phase 2: 300 upper-tri pairs + 25 diagonal zeros.
    const float alpha = Aarr[0];
    float* outb = out + (size_t)b * (NJ * NJ);

    if (t < 300) {
        int i = (int)((49.0f - sqrtf(2401.0f - 8.0f * (float)t)) * 0.5f);
        {   // fp-safety clamp
            int Si = (49 * i - i * i) >> 1;
            if (t < Si) { --i; }
            else { int Sn = (49 * (i + 1) - (i + 1) * (i + 1)) >> 1; if (t >= Sn) ++i; }
        }
        const int S = (49 * i - i * i) >> 1;
        const int j = t - S + i + 1;

        const float* uj = u_s + j * 132;
        const float* ui = u_s + i * 132;
        const float4* w2v = (const float4*)W2;   // uniform -> s_load

        float M = 0.f, sj = 0.f, si = 0.f;
        #pragma unroll 8
        for (int h4 = 0; h4 < 32; ++h4) {
            float4 a = *(const float4*)(uj + h4 * 4);
            float4 c = *(const float4*)(ui + h4 * 4);
            float4 ww = w2v[h4];
            M  = fmaf(ww.x, fmaxf(a.x, c.x), M); sj = fmaf(ww.x, a.x, sj); si = fmaf(ww.x, c.x, si);
            M  = fmaf(ww.y, fmaxf(a.y, c.y), M); sj = fmaf(ww.y, a.y, sj); si = fmaf(ww.y, c.y, si);
            M  = fmaf(ww.z, fmaxf(a.z, c.z), M); sj = fmaf(ww.z, a.z, sj); si = fmaf(ww.z, c.z, si);
            M  = fmaf(ww.w, fmaxf(a.w, c.w), M); sj = fmaf(ww.w, a.w, sj); si = fmaf(ww.w, c.w, si);
        }
        const float Mw = (1.f - alpha) * M;
        outb[i * NJ + j] = Mw + alpha * sj - si;
        outb[j * NJ + i] = Mw + alpha * si - sj;
    } else if (t < 325) {
        const int i = t - 300;
        outb[i * (NJ + 1)] = 0.f;     // diagonal: d=0 -> prelu=0 exactly
    }
}

extern "C" void kernel_launch(void* const* d_in, const int* in_sizes, int n_in,
                              void* d_out, int out_size, void* d_ws, size_t ws_size,
                              hipStream_t stream) {
    // inputs: 0=src, 1=heads, 2=ends, 3=pair_ids (unused: telescoping), 4=W1, 5=alpha, 6=W2
    const float* src   = (const float*)d_in[0];
    const float* W1    = (const float*)d_in[4];
    const float* alpha = (const float*)d_in[5];
    const float* W2    = (const float*)d_in[6];
    float* out = (float*)d_out;

    const int B    = in_sizes[0] / (NJ * CIN);          // 256
    const int nsrc = B * 16 * 64;                        // src fragment chunks
    unsigned short* srcfrag = (unsigned short*)d_ws;     // nsrc*16 B  (~4.2 MB)
    unsigned short* w1frag  = srcfrag + (size_t)nsrc * 8; // 4096*16 B (64 KB)

    const int totalA = nsrc + 4096;
    prep_frags<<<(totalA + 255) / 256, 256, 0, stream>>>(src, W1, srcfrag, w1frag, nsrc);
    fused_edge_mlp_v4<<<B, 512, 0, stream>>>(srcfrag, w1frag, alpha, W2, out);
}